// Round 11
// baseline (596.651 us; speedup 1.0000x reference)
//
#include <hip/hip_runtime.h>

typedef __bf16 bf16f __attribute__((ext_vector_type(8)));
typedef float  f32x4 __attribute__((ext_vector_type(4)));

union bfpack { bf16f v; uint4 u; };

__device__ __forceinline__ float bf2f(unsigned short u) {
  union { unsigned int u; float f; } v;
  v.u = ((unsigned int)u) << 16;
  return v.f;
}
__device__ __forceinline__ unsigned short f2bf(float f) {
  union { float f; unsigned int u; } v; v.f = f;
  unsigned int r = v.u + 0x7FFFu + ((v.u >> 16) & 1u);
  return (unsigned short)(r >> 16);
}
__device__ __forceinline__ float bflo(unsigned int w) {
  union { unsigned int u; float f; } v; v.u = w << 16; return v.f;
}
__device__ __forceinline__ float bfhi(unsigned int w) {
  union { unsigned int u; float f; } v; v.u = w & 0xFFFF0000u; return v.f;
}

// zero the degree counters (canonical kernel symbol kept here)
__global__ void GNNModel_general_12077448036407_kernel(int* cnt, int ncnt) {
  int i = blockIdx.x * blockDim.x + threadIdx.x;
  if (i < ncnt) cnt[i] = 0;
}

// ---------------- CSR build (graph shared by both GAT layers) ----------------
__global__ void rank_kernel(const int* __restrict__ dst, int* __restrict__ cnt,
                            unsigned short* __restrict__ rank, int E) {
  int e = blockIdx.x * blockDim.x + threadIdx.x;
  if (e < E) {
    int r = atomicAdd(&cnt[dst[e]], 1);
    rank[e] = (unsigned short)r;
  }
}

__global__ void scan1_kernel(const int* __restrict__ cnt, int* __restrict__ offs,
                             int* __restrict__ bsum, int M) {
  __shared__ int sh[256];
  int t = threadIdx.x;
  int i = blockIdx.x * 256 + t;
  int v = (i < M) ? cnt[i] : 0;
  sh[t] = v;
  __syncthreads();
  for (int off = 1; off < 256; off <<= 1) {
    int u = (t >= off) ? sh[t - off] : 0;
    __syncthreads();
    sh[t] += u;
    __syncthreads();
  }
  if (i <= M) offs[i] = sh[t] - v;
  if (t == 255) bsum[blockIdx.x] = sh[255];
}

__global__ void scan2_kernel(int* __restrict__ bsum, int NB) {
  __shared__ int sh[256];
  int t = threadIdx.x;
  int v = (t < NB) ? bsum[t] : 0;
  sh[t] = v;
  __syncthreads();
  for (int off = 1; off < 256; off <<= 1) {
    int u = (t >= off) ? sh[t - off] : 0;
    __syncthreads();
    sh[t] += u;
    __syncthreads();
  }
  if (t < NB) bsum[t] = sh[t] - v;
}

__global__ void scan3_kernel(int* __restrict__ offs, const int* __restrict__ bsum, int M) {
  int i = blockIdx.x * 256 + threadIdx.x;
  if (i <= M) offs[i] += bsum[i >> 8];
}

__global__ void place_kernel(const int* __restrict__ src, const int* __restrict__ dst,
                             const unsigned short* __restrict__ rank,
                             const int* __restrict__ offs, int* __restrict__ csr_src, int E) {
  int e = blockIdx.x * blockDim.x + threadIdx.x;
  if (e < E) {
    int p = offs[dst[e]] + (int)rank[e];
    __builtin_nontemporal_store(src[e], &csr_src[p]);
  }
}

// ---------------- weight prep: f32 [k][n] -> bf16 [n][k] (B-frag layout) -----
// lw1 [128][512]->lw1b[512][128]; lw2 [512][256]->lw2b[256][512];
// lw3 [256][16]->lw3b[16][256]
__global__ void wprep_kernel(const float* __restrict__ lw1, const float* __restrict__ lw2,
                             const float* __restrict__ lw3,
                             unsigned short* __restrict__ lw1b,
                             unsigned short* __restrict__ lw2b,
                             unsigned short* __restrict__ lw3b) {
  int i = blockIdx.x * blockDim.x + threadIdx.x;
  if (i < 512 * 128) {
    int n = i >> 7, k = i & 127;
    lw1b[i] = f2bf(lw1[k * 512 + n]);
    return;
  }
  int j = i - 512 * 128;
  if (j < 256 * 512) {
    int n = j >> 9, k = j & 511;
    lw2b[j] = f2bf(lw2[k * 256 + n]);
    return;
  }
  int l = j - 256 * 512;
  if (l < 16 * 256) {
    int n = l >> 8, k = l & 255;
    lw3b[l] = f2bf(lw3[k * 16 + n]);
  }
}

// ---------------- fused MLP head: emb[M,128] -> logits[M,16] -----------------
// 192 threads = 3 independent waves, 16 rows each (no __syncthreads at all).
// Per wave: phase1 z1=relu(emb@lw1+b1) -> private LDS strip (A-layout, pitch 520);
// phase2 caches all 16 A-frags in regs, 256 MFMAs vs L2-resident lw2b, writes
// z2 back into the (now dead) strip; phase3 8 MFMAs vs lw3b -> logits.
// MFMA layouts (m89): A[m=lane&15][k=(lane>>4)*8+j], B[k][n=lane&15],
// D row=(lane>>4)*4+reg, col=lane&15.
__launch_bounds__(192)
__global__ void fmlp_kernel(const float* __restrict__ emb,
                            const unsigned short* __restrict__ lw1b, const float* __restrict__ lb1,
                            const unsigned short* __restrict__ lw2b, const float* __restrict__ lb2,
                            const unsigned short* __restrict__ lw3b, const float* __restrict__ lb3,
                            float* __restrict__ logits, int M) {
  __shared__ unsigned short z1s[3][16 * 520];   // 49,920 B
  int tid = threadIdx.x;
  int wave = tid >> 6, lane = tid & 63;
  int lm = lane & 15, quad = lane >> 4;
  int r0 = blockIdx.x * 48 + wave * 16;
  unsigned short* zs = &z1s[wave][0];

  // phase-1 A-frags: emb row r0+lm, K=128 (4 chunks), f32->bf16 in regs
  bfpack a1[4];
  int m = r0 + lm;
  if (m < M) {
    const float* ep = emb + (size_t)m * 128 + quad * 8;
#pragma unroll
    for (int c = 0; c < 4; c++) {
      float4 u = *(const float4*)(ep + c * 32);
      float4 w = *(const float4*)(ep + c * 32 + 4);
      a1[c].u.x = (unsigned int)f2bf(u.x) | ((unsigned int)f2bf(u.y) << 16);
      a1[c].u.y = (unsigned int)f2bf(u.z) | ((unsigned int)f2bf(u.w) << 16);
      a1[c].u.z = (unsigned int)f2bf(w.x) | ((unsigned int)f2bf(w.y) << 16);
      a1[c].u.w = (unsigned int)f2bf(w.z) | ((unsigned int)f2bf(w.w) << 16);
    }
  } else {
#pragma unroll
    for (int c = 0; c < 4; c++) { a1[c].u.x = 0; a1[c].u.y = 0; a1[c].u.z = 0; a1[c].u.w = 0; }
  }

  // phase 1: z1[16][512]
  for (int cb = 0; cb < 32; cb++) {
    f32x4 acc;
#pragma unroll
    for (int i = 0; i < 4; i++) acc[i] = 0.0f;
    const unsigned short* bp = lw1b + ((cb * 16 + lm) << 7) + quad * 8;
#pragma unroll
    for (int c = 0; c < 4; c++) {
      bfpack bf; bf.u = *(const uint4*)(bp + c * 32);
      acc = __builtin_amdgcn_mfma_f32_16x16x32_bf16(a1[c].v, bf.v, acc, 0, 0, 0);
    }
    float bv = lb1[cb * 16 + lm];
#pragma unroll
    for (int i = 0; i < 4; i++) {
      float v = fmaxf(acc[i] + bv, 0.0f);
      zs[(quad * 4 + i) * 520 + cb * 16 + lm] = f2bf(v);
    }
  }

  // phase 2: cache all A-frags (z1 strip) in regs, then z2[16][256]
  bfpack a2[16];
#pragma unroll
  for (int c = 0; c < 16; c++)
    a2[c].u = *(const uint4*)&zs[lm * 520 + c * 32 + quad * 8];

  for (int cb = 0; cb < 16; cb++) {
    f32x4 acc;
#pragma unroll
    for (int i = 0; i < 4; i++) acc[i] = 0.0f;
    const unsigned short* bp = lw2b + ((cb * 16 + lm) << 9) + quad * 8;
#pragma unroll
    for (int c = 0; c < 16; c++) {
      bfpack bf; bf.u = *(const uint4*)(bp + c * 32);
      acc = __builtin_amdgcn_mfma_f32_16x16x32_bf16(a2[c].v, bf.v, acc, 0, 0, 0);
    }
    float bv = lb2[cb * 16 + lm];
#pragma unroll
    for (int i = 0; i < 4; i++) {
      float v = fmaxf(acc[i] + bv, 0.0f);
      zs[(quad * 4 + i) * 520 + cb * 16 + lm] = f2bf(v);   // z2 overwrites dead z1
    }
  }

  // phase 3: logits[16][16], K=256
  f32x4 acc3;
#pragma unroll
  for (int i = 0; i < 4; i++) acc3[i] = 0.0f;
  const unsigned short* bp3 = lw3b + (lm << 8) + quad * 8;
#pragma unroll
  for (int c = 0; c < 8; c++) {
    bfpack af; af.u = *(const uint4*)&zs[lm * 520 + c * 32 + quad * 8];
    bfpack bf; bf.u = *(const uint4*)(bp3 + c * 32);
    acc3 = __builtin_amdgcn_mfma_f32_16x16x32_bf16(af.v, bf.v, acc3, 0, 0, 0);
  }
  float bv3 = lb3[lm];
#pragma unroll
  for (int i = 0; i < 4; i++) {
    int row = r0 + quad * 4 + i;
    if (row < M) logits[(size_t)row * 16 + lm] = acc3[i] + bv3;
  }
}

// ---------------- tiled f32 GEMM (GAT layers; f32 accumulate) ----------------
__launch_bounds__(256)
__global__ void tgemm_kernel(const void* __restrict__ A, const float* __restrict__ W,
                             const float* __restrict__ bias, void* __restrict__ C,
                             int M, int K, int Nt, int aBF, int cBF, int relu) {
  __shared__ float As[16][132];
  __shared__ float Bs[16][136];
  int t = threadIdx.x;
  int tx = t & 15, ty = t >> 4;
  int m0 = blockIdx.x * 128, n0 = blockIdx.y * 128;

  float acc[8][8];
#pragma unroll
  for (int i = 0; i < 8; i++)
#pragma unroll
    for (int j = 0; j < 8; j++) acc[i][j] = 0.0f;

  int arow = t >> 1;
  int akc  = (t & 1) * 8;
  int bkk  = t >> 4;
  int bnn  = (t & 15) * 8;
  int gm = m0 + arow;

  for (int k0 = 0; k0 < K; k0 += 16) {
    float av[8];
    if (gm < M) {
      if (aBF) {
        const unsigned short* Ab = (const unsigned short*)A + (size_t)gm * K + k0 + akc;
        uint4 raw = *(const uint4*)Ab;
        av[0] = bflo(raw.x); av[1] = bfhi(raw.x);
        av[2] = bflo(raw.y); av[3] = bfhi(raw.y);
        av[4] = bflo(raw.z); av[5] = bfhi(raw.z);
        av[6] = bflo(raw.w); av[7] = bfhi(raw.w);
      } else {
        const float* Af = (const float*)A + (size_t)gm * K + k0 + akc;
        float4 r0 = *(const float4*)Af;
        float4 r1 = *(const float4*)(Af + 4);
        av[0] = r0.x; av[1] = r0.y; av[2] = r0.z; av[3] = r0.w;
        av[4] = r1.x; av[5] = r1.y; av[6] = r1.z; av[7] = r1.w;
      }
    } else {
#pragma unroll
      for (int j = 0; j < 8; j++) av[j] = 0.0f;
    }
#pragma unroll
    for (int j = 0; j < 8; j++) As[akc + j][arow] = av[j];

    const float* bp = W + (size_t)(k0 + bkk) * Nt + n0 + bnn;
    float4 b0 = *(const float4*)bp;
    float4 b1 = *(const float4*)(bp + 4);
    *(float4*)&Bs[bkk][bnn]     = b0;
    *(float4*)&Bs[bkk][bnn + 4] = b1;

    __syncthreads();

#pragma unroll 4
    for (int kk = 0; kk < 16; kk++) {
      float a[8], b[8];
      *(float4*)&a[0] = *(const float4*)&As[kk][ty * 8];
      *(float4*)&a[4] = *(const float4*)&As[kk][ty * 8 + 4];
      *(float4*)&b[0] = *(const float4*)&Bs[kk][tx * 8];
      *(float4*)&b[4] = *(const float4*)&Bs[kk][tx * 8 + 4];
#pragma unroll
      for (int i = 0; i < 8; i++)
#pragma unroll
        for (int j = 0; j < 8; j++)
          acc[i][j] = fmaf(a[i], b[j], acc[i][j]);
    }
    __syncthreads();
  }

  float bv[8];
#pragma unroll
  for (int j = 0; j < 8; j++) bv[j] = (bias != 0) ? bias[n0 + tx * 8 + j] : 0.0f;

#pragma unroll
  for (int i = 0; i < 8; i++) {
    int m = m0 + ty * 8 + i;
    if (m >= M) continue;
    float v[8];
#pragma unroll
    for (int j = 0; j < 8; j++) {
      float s = acc[i][j] + bv[j];
      v[j] = relu ? fmaxf(s, 0.0f) : s;
    }
    if (cBF) {
      unsigned short* Cp = (unsigned short*)C + (size_t)m * Nt + n0 + tx * 8;
      uint4 pk;
      pk.x = (unsigned int)f2bf(v[0]) | ((unsigned int)f2bf(v[1]) << 16);
      pk.y = (unsigned int)f2bf(v[2]) | ((unsigned int)f2bf(v[3]) << 16);
      pk.z = (unsigned int)f2bf(v[4]) | ((unsigned int)f2bf(v[5]) << 16);
      pk.w = (unsigned int)f2bf(v[6]) | ((unsigned int)f2bf(v[7]) << 16);
      *(uint4*)Cp = pk;
    } else {
      float* Cp = (float*)C + (size_t)m * Nt + n0 + tx * 8;
      float4 o0; o0.x = v[0]; o0.y = v[1]; o0.z = v[2]; o0.w = v[3];
      float4 o1; o1.x = v[4]; o1.y = v[5]; o1.z = v[6]; o1.w = v[7];
      *(float4*)Cp = o0;
      *(float4*)(Cp + 4) = o1;
    }
  }
}

// ---------------- per-node attention coefficients (h is bf16) ----------------
__global__ void alphas_kernel(const unsigned short* __restrict__ hb,
                              const float* __restrict__ a_src,
                              const float* __restrict__ a_dst,
                              float2* __restrict__ aSp, float2* __restrict__ aDp, int M) {
  int gw = (blockIdx.x * blockDim.x + threadIdx.x) >> 6;
  int lane = threadIdx.x & 63;
  if (gw >= M) return;
  float h0 = bf2f(hb[(size_t)gw * 128 + lane]);
  float h1 = bf2f(hb[(size_t)gw * 128 + 64 + lane]);
  float as0 = h0 * a_src[lane];
  float as1 = h1 * a_src[64 + lane];
  float ad0 = h0 * a_dst[lane];
  float ad1 = h1 * a_dst[64 + lane];
  for (int o = 32; o; o >>= 1) {
    as0 += __shfl_xor(as0, o);
    as1 += __shfl_xor(as1, o);
    ad0 += __shfl_xor(ad0, o);
    ad1 += __shfl_xor(ad1, o);
  }
  if (lane == 0) {
    aSp[gw] = make_float2(as0, as1);
    aDp[gw] = make_float2(ad0, ad1);
  }
}

// ---------------- per-node softmax aggregation (bf16 gather, 4 edges/iter) ----
__global__ void aggregate_kernel(const unsigned short* __restrict__ hb,
                                 const float2* __restrict__ aSp,
                                 const float2* __restrict__ aDp,
                                 const int* __restrict__ csr_src, const int* __restrict__ offs,
                                 const float* __restrict__ bias,
                                 float* __restrict__ out, int M) {
  int n = (blockIdx.x * blockDim.x + threadIdx.x) >> 6;
  int lane = threadIdx.x & 63;
  if (n >= M) return;
  int g = lane >> 4;
  int q = lane & 15;
  int h0sel = (q < 8);

  float2 adn = aDp[n];
  float2 asn = aSp[n];
  float e0 = asn.x + adn.x; e0 = (e0 > 0.0f) ? e0 : 0.2f * e0;   // leaky_relu 0.2
  float e1 = asn.y + adn.y; e1 = (e1 > 0.0f) ? e1 : 0.2f * e1;
  float ws0 = expf(e0), ws1 = expf(e1);
  float wself = h0sel ? ws0 : ws1;

  float acc[8];
  if (g == 0) {
    uint4 rv = *(const uint4*)(hb + (size_t)n * 128 + q * 8);
    acc[0] = wself * bflo(rv.x); acc[1] = wself * bfhi(rv.x);
    acc[2] = wself * bflo(rv.y); acc[3] = wself * bfhi(rv.y);
    acc[4] = wself * bflo(rv.z); acc[5] = wself * bfhi(rv.z);
    acc[6] = wself * bflo(rv.w); acc[7] = wself * bfhi(rv.w);
  } else {
#pragma unroll
    for (int i = 0; i < 8; i++) acc[i] = 0.0f;
  }

  float lp0 = 0.0f, lp1 = 0.0f;
  int rs = offs[n], re = offs[n + 1];
  for (int base = rs; base < re; base += 64) {
    int cnt = re - base; if (cnt > 64) cnt = 64;
    int s = 0; float w0 = 0.0f, w1 = 0.0f;
    if (lane < cnt) {
      s = csr_src[base + lane];
      float2 a = aSp[s];
      float f0 = a.x + adn.x; f0 = (f0 > 0.0f) ? f0 : 0.2f * f0;
      float f1 = a.y + adn.y; f1 = (f1 > 0.0f) ? f1 : 0.2f * f1;
      w0 = expf(f0); w1 = expf(f1);
      lp0 += w0; lp1 += w1;
    }
    int jmax = (cnt + 3) >> 2;
#pragma unroll 2
    for (int j = 0; j < jmax; j++) {
      int el = 4 * j + g;
      int sj  = __shfl(s, el);
      float w0j = __shfl(w0, el);
      float w1j = __shfl(w1, el);
      float wj = h0sel ? w0j : w1j;
      uint4 rv = *(const uint4*)(hb + (size_t)sj * 128 + q * 8);
      acc[0] = fmaf(wj, bflo(rv.x), acc[0]);
      acc[1] = fmaf(wj, bfhi(rv.x), acc[1]);
      acc[2] = fmaf(wj, bflo(rv.y), acc[2]);
      acc[3] = fmaf(wj, bfhi(rv.y), acc[3]);
      acc[4] = fmaf(wj, bflo(rv.z), acc[4]);
      acc[5] = fmaf(wj, bfhi(rv.z), acc[5]);
      acc[6] = fmaf(wj, bflo(rv.w), acc[6]);
      acc[7] = fmaf(wj, bfhi(rv.w), acc[7]);
    }
  }
#pragma unroll
  for (int i = 0; i < 8; i++) {
    acc[i] += __shfl_xor(acc[i], 16);
    acc[i] += __shfl_xor(acc[i], 32);
  }
  for (int o = 32; o; o >>= 1) {
    lp0 += __shfl_xor(lp0, o);
    lp1 += __shfl_xor(lp1, o);
  }
  if (g == 0) {
    float linv = 1.0f / ((h0sel ? lp0 + ws0 : lp1 + ws1) + 1e-16f);
    const float* bp = bias + q * 8;
    float4 o0, o1;
    o0.x = fmaxf(acc[0] * linv + bp[0], 0.0f);
    o0.y = fmaxf(acc[1] * linv + bp[1], 0.0f);
    o0.z = fmaxf(acc[2] * linv + bp[2], 0.0f);
    o0.w = fmaxf(acc[3] * linv + bp[3], 0.0f);
    o1.x = fmaxf(acc[4] * linv + bp[4], 0.0f);
    o1.y = fmaxf(acc[5] * linv + bp[5], 0.0f);
    o1.z = fmaxf(acc[6] * linv + bp[6], 0.0f);
    o1.w = fmaxf(acc[7] * linv + bp[7], 0.0f);
    float* op = out + (size_t)n * 128 + q * 8;
    *(float4*)op = o0;
    *(float4*)(op + 4) = o1;
  }
}

extern "C" void kernel_launch(void* const* d_in, const int* in_sizes, int n_in,
                              void* d_out, int out_size, void* d_ws, size_t ws_size,
                              hipStream_t stream) {
  const int N = in_sizes[0] / 64;   // 50000
  const int E = in_sizes[1] / 2;    // 1,600,000
  const float* x   = (const float*)d_in[0];
  const int*   ei  = (const int*)d_in[1];
  const float* W1  = (const float*)d_in[2];
  const float* as1 = (const float*)d_in[3];
  const float* ad1 = (const float*)d_in[4];
  const float* b1  = (const float*)d_in[5];
  const float* W2  = (const float*)d_in[6];
  const float* as2 = (const float*)d_in[7];
  const float* ad2 = (const float*)d_in[8];
  const float* b2  = (const float*)d_in[9];
  const float* lw1 = (const float*)d_in[10];
  const float* lb1 = (const float*)d_in[11];
  const float* lw2 = (const float*)d_in[12];
  const float* lb2 = (const float*)d_in[13];
  const float* lw3 = (const float*)d_in[14];
  const float* lb3 = (const float*)d_in[15];

  float* emb    = (float*)d_out;                    // N*128 f32
  float* logits = (float*)d_out + (size_t)N * 128;  // N*16 f32

  // ---- workspace layout ----
  char* base = (char*)d_ws;
  size_t o = 0;
  unsigned short* hb = (unsigned short*)(base + o); o += ((size_t)N * 128 * 2 + 255) & ~(size_t)255;
  float* x2f = (float*)(base + o); o += ((size_t)N * 128 * 4 + 255) & ~(size_t)255;
  float2* aSp = (float2*)(base + o); o += ((size_t)N * 8 + 255) & ~(size_t)255;
  float2* aDp = (float2*)(base + o); o += ((size_t)N * 8 + 255) & ~(size_t)255;
  int* cnt  = (int*)(base + o); o += ((size_t)N * 4 + 255) & ~(size_t)255;
  int* offs = (int*)(base + o); o += ((size_t)(N + 1) * 4 + 255) & ~(size_t)255;
  int* bsum = (int*)(base + o); o += ((size_t)256 * 4 + 255) & ~(size_t)255;
  unsigned short* rank = (unsigned short*)(base + o); o += ((size_t)E * 2 + 255) & ~(size_t)255;
  int* csr  = (int*)(base + o); o += ((size_t)E * 4 + 255) & ~(size_t)255;
  unsigned short* lw1b = (unsigned short*)(base + o); o += ((size_t)512 * 128 * 2 + 255) & ~(size_t)255;
  unsigned short* lw2b = (unsigned short*)(base + o); o += ((size_t)256 * 512 * 2 + 255) & ~(size_t)255;
  unsigned short* lw3b = (unsigned short*)(base + o); o += ((size_t)16 * 256 * 2 + 255) & ~(size_t)255;

  const int* esrc = ei;
  const int* edst = ei + E;

  // weight prep (independent of everything else)
  {
    int tot = 512 * 128 + 256 * 512 + 16 * 256;
    wprep_kernel<<<(tot + 255) / 256, 256, 0, stream>>>(lw1, lw2, lw3, lw1b, lw2b, lw3b);
  }

  // CSR build: zero -> rank -> scan(x3) -> place
  GNNModel_general_12077448036407_kernel<<<(N + 255) / 256, 256, 0, stream>>>(cnt, N);
  int eb = (E + 255) / 256;
  rank_kernel<<<eb, 256, 0, stream>>>(edst, cnt, rank, E);
  int sb = (N + 256) / 256;
  scan1_kernel<<<sb, 256, 0, stream>>>(cnt, offs, bsum, N);
  scan2_kernel<<<1, 256, 0, stream>>>(bsum, sb);
  scan3_kernel<<<sb, 256, 0, stream>>>(offs, bsum, N);
  place_kernel<<<eb, 256, 0, stream>>>(esrc, edst, rank, offs, csr, E);

  int nb4 = (N + 3) / 4;
  int mtb = (N + 127) / 128;

  // GAT layer 1: hb = bf16(x @ W1)
  tgemm_kernel<<<dim3(mtb, 1), 256, 0, stream>>>(x, W1, (const float*)0, hb,
                                                 N, 64, 128, 0, 1, 0);
  alphas_kernel<<<nb4, 256, 0, stream>>>(hb, as1, ad1, aSp, aDp, N);
  aggregate_kernel<<<nb4, 256, 0, stream>>>(hb, aSp, aDp, csr, offs, b1, x2f, N);

  // GAT layer 2: hb = bf16(x2 @ W2)
  tgemm_kernel<<<dim3(mtb, 1), 256, 0, stream>>>(x2f, W2, (const float*)0, hb,
                                                 N, 128, 128, 0, 1, 0);
  alphas_kernel<<<nb4, 256, 0, stream>>>(hb, as2, ad2, aSp, aDp, N);
  aggregate_kernel<<<nb4, 256, 0, stream>>>(hb, aSp, aDp, csr, offs, b2, emb, N);

  // fused MLP head: emb -> logits (z1/z2 never touch HBM)
  {
    int fb = (N + 47) / 48;
    fmlp_kernel<<<fb, 192, 0, stream>>>(emb, lw1b, lb1, lw2b, lb2, lw3b, lb3, logits, N);
  }
}